// Round 3
// baseline (585.654 us; speedup 1.0000x reference)
//
#include <hip/hip_runtime.h>

#define NSPL 191                 // 3*64 - 1 spline dims
constexpr float MIN_W = 0.001f, MIN_H = 0.001f, MIN_D = 0.001f;
constexpr float W_A = -10000.0f, AB = 20000.0f;
constexpr float LOG_HALF = -0.69314718055994530942f;
constexpr float LOG_AB   = 9.90348755253612804622f;   // ln(20000)

#define CPB 256     // cuts per block == threads per block (thread t <-> cut i0+t)
#define TC  32      // tile columns
#define PITCH 33    // LDS row pitch (+1 pad: banks (t+j)%32, conflict-free)

// Thread-per-cut RQS inverse logdet.
// Stage delta_spline cols [0,128) through LDS tiles (coalesced), exp to regs:
//   - w-half (cols 0..63): only the softmax SUM is needed (in_cw unused by logdet)
//   - h-half (cols 64..127): eh[64] kept in registers for the bin-search loop
// d0/d1/ew_idx/eh_idx re-fetched from global at known offsets (L1/L2-hit).
__global__ __launch_bounds__(CPB, 3) void rqs_tpc_kernel(
    const float* __restrict__ value,
    const float* __restrict__ dsg,       // delta_spline
    const int*   __restrict__ genes_oi,
    const int*   __restrict__ lgi,
    const float* __restrict__ sw,
    float* __restrict__ out, int n)
{
    __shared__ float tile[CPB * PITCH];

    const int t  = threadIdx.x;
    const int i0 = blockIdx.x * CPB;
    const int i  = i0 + t;
    const int ic = min(i, n - 1);

    const int g = genes_oi[lgi[ic]];
    const float* __restrict__ swr = sw  + (long)g  * NSPL;
    const float* __restrict__ dsr = dsg + (long)ic * NSPL;

    const float v = value[ic];
    float x = fmaf(v - W_A, 2.0f / AB, -1.0f);
    const bool inside = (x >= -1.0f) && (x <= 1.0f);
    x = fminf(fmaxf(x, -1.0f), 1.0f);

    float eh[64];                       // h-half exp values (register-resident)
    float s0 = 0.f, s1 = 0.f, s2a = 0.f, s3 = 0.f;   // Sw partial accumulators
    float h0 = 0.f, h1 = 0.f, h2a = 0.f, h3 = 0.f;   // Sh partial accumulators

    const int c  = t & (TC - 1);        // 0..31
    const int r0 = t >> 5;              // 0..7 (8 rows per load inst)

    #pragma unroll
    for (int tt = 0; tt < 4; ++tt) {
        const int jc = tt * TC;         // global col base: 0,32,64,96

        // ---- coalesced global -> regs -> LDS (rows i0..i0+255, cols jc..jc+31)
        float tmp[32];
        #pragma unroll
        for (int rr = 0; rr < 32; ++rr) {
            const int r  = r0 + (rr << 3);
            const int rg = min(i0 + r, n - 1);
            tmp[rr] = dsg[(long)rg * NSPL + jc + c];
        }
        #pragma unroll
        for (int rr = 0; rr < 32; ++rr) {
            const int r = r0 + (rr << 3);
            tile[r * PITCH + c] = tmp[rr];
        }
        __syncthreads();

        // ---- per-thread: read own row's tile cols, add gene row, exp
        #pragma unroll
        for (int j = 0; j < TC; ++j) {
            const float u = tile[t * PITCH + j] + swr[jc + j];
            const float e = __expf(u);
            if (tt < 2) {               // w-half: only the sum matters
                if ((j & 3) == 0) s0 += e;
                else if ((j & 3) == 1) s1 += e;
                else if ((j & 3) == 2) s2a += e;
                else s3 += e;
            } else {                    // h-half: keep values + sum
                eh[jc + j - 64] = e;
                if ((j & 3) == 0) h0 += e;
                else if ((j & 3) == 1) h1 += e;
                else if ((j & 3) == 2) h2a += e;
                else h3 += e;
            }
        }
        __syncthreads();
    }

    const float Sw = (s0 + s1) + (s2a + s3);
    const float Sh = (h0 + h1) + (h2a + h3);
    const float wsc2 = 2.0f * __fdividef(1.0f - MIN_W * 64.0f, Sw);
    const float hsc2 = 2.0f * __fdividef(1.0f - MIN_H * 64.0f, Sh);

    // ---- bin search + prefix capture (monotone; right edge j: j<=62 only)
    float Eh = 0.0f, capEh = 0.0f;
    int idx = 0;
    #pragma unroll
    for (int j = 0; j < 63; ++j) {
        Eh += eh[j];
        const float chr = fmaf(hsc2, Eh, 2.0f * MIN_H * (float)(j + 1) - 1.0f);
        const bool take = (x >= chr);
        idx  += take ? 1 : 0;
        capEh = take ? Eh : capEh;      // ends as Eh_{idx-1} (0 if idx==0)
    }

    // ---- epilogue: scattered reloads at known cols (L1/L2-hit)
    const float ew_i = __expf(dsr[idx]      + swr[idx]);
    const float eh_i = __expf(dsr[64 + idx] + swr[64 + idx]);
    const int c0 = 127 + max(idx, 1);       // ud col for d0 (idx>=1)
    const int c1 = 128 + min(idx, 62);      // ud col for d1 (idx<=62)
    const float u0 = dsr[c0] + swr[c0];
    const float u1 = dsr[c1] + swr[c1];
    const float d0 = (idx == 0)  ? 1.0f : (MIN_D + __logf(1.0f + __expf(u0)));
    const float d1 = (idx == 63) ? 1.0f : (MIN_D + __logf(1.0f + __expf(u1)));

    const float in_w = fmaf(wsc2, ew_i, 2.0f * MIN_W);
    const float in_h = fmaf(hsc2, eh_i, 2.0f * MIN_H);
    const float ch_l = fmaf(hsc2, capEh, fmaf(2.0f * MIN_H, (float)idx, -1.0f));

    const float delta = __fdividef(in_h, in_w);
    const float dy = x - ch_l;
    const float ss = d0 + d1 - 2.0f * delta;
    const float aa = dy * ss + in_h * (delta - d0);
    const float bb = in_h * d0 - dy * ss;
    const float cc = -delta * dy;
    const float disc = bb * bb - 4.0f * aa * cc;
    const float root = __fdividef(2.0f * cc, -bb - sqrtf(fmaxf(disc, 0.0f)));
    const float tom = root * (1.0f - root);
    const float denom = delta + ss * tom;
    const float omr = 1.0f - root;
    const float dnum = delta * delta * (d1 * root * root + 2.0f * delta * tom + d0 * omr * omr);
    const float logabsdet = -(__logf(dnum) - 2.0f * __logf(denom));

    if (i < n)
        out[i] = LOG_HALF + (inside ? logabsdet : 0.0f) - LOG_AB;
}

extern "C" void kernel_launch(void* const* d_in, const int* in_sizes, int n_in,
                              void* d_out, int out_size, void* d_ws, size_t ws_size,
                              hipStream_t stream) {
    const float* value         = (const float*)d_in[0];
    const float* delta_spline  = (const float*)d_in[1];
    const int*   genes_oi      = (const int*)d_in[2];
    const int*   local_gene_ix = (const int*)d_in[3];
    const float* spline_weight = (const float*)d_in[4];
    float* out = (float*)d_out;

    const int n = in_sizes[0];
    const int blocks = (n + CPB - 1) / CPB;
    rqs_tpc_kernel<<<blocks, CPB, 0, stream>>>(
        value, delta_spline, genes_oi, local_gene_ix, spline_weight, out, n);
}

// Round 4
// 500.979 us; speedup vs baseline: 1.1690x; 1.1690x over previous
//
#include <hip/hip_runtime.h>

#define NSPL 191                 // 3*64 - 1 spline dims
constexpr float MIN_W = 0.001f, MIN_H = 0.001f, MIN_D = 0.001f;
constexpr float W_A = -10000.0f, AB = 20000.0f;
constexpr float LOG_HALF = -0.69314718055994530942f;
constexpr float LOG_AB   = 9.90348755253612804622f;   // ln(20000)

// 4-float vector with only 4B alignment (spline rows are 191 floats -> odd base)
typedef float f4 __attribute__((ext_vector_type(4), aligned(4)));

// DPP add: x += dpp(x); bound_ctrl=1 -> shifted-in lanes contribute 0
template<int CTRL>
__device__ __forceinline__ float dpp_add(float x) {
    int t = __builtin_amdgcn_update_dpp(0, __float_as_int(x), CTRL, 0xf, 0xf, true);
    return x + __int_as_float(t);
}
template<int PAT>
__device__ __forceinline__ float swz_f(float x) {
    return __int_as_float(__builtin_amdgcn_ds_swizzle(__float_as_int(x), PAT));
}
template<int PAT>
__device__ __forceinline__ int swz_i(int x) {
    return __builtin_amdgcn_ds_swizzle(x, PAT);
}

// 16 lanes per cut, 4 cuts per wave. Lane `sub` (0..15) owns bins 4*sub..4*sub+3.
__global__ __launch_bounds__(256, 4) void rqs_g16_kernel(
    const float* __restrict__ value,
    const float* __restrict__ dsg,       // delta_spline [n,191]
    const int*   __restrict__ genes_oi,
    const int*   __restrict__ lgi,
    const float* __restrict__ swg,       // spline_weight [5000,191]
    float* __restrict__ out, int n)
{
    const int lane = threadIdx.x & 63;
    const int sub  = lane & 15;
    const int grp  = lane >> 4;
    const int wv   = threadIdx.x >> 6;
    const long ii  = (long)blockIdx.x * 16 + wv * 4 + grp;   // cut index
    const int  ic  = (int)(ii < (long)n ? ii : (long)(n - 1));

    // group-uniform scalars (same address across the 16 lanes of a group)
    const int g = genes_oi[lgi[ic]];
    const float v = value[ic];

    const float* __restrict__ dsr = dsg + (long)ic * NSPL;
    const float* __restrict__ swr = swg + (long)g  * NSPL;

    // ---- coalesced row-segment loads: 4 w-cols + 4 h-cols per lane ----
    const int cb = 4 * sub;
    const f4 dw = *(const f4*)(dsr + cb);
    const f4 dh = *(const f4*)(dsr + 64 + cb);
    const f4 ww = *(const f4*)(swr + cb);
    const f4 wh = *(const f4*)(swr + 64 + cb);

    // ---- x ----
    float x = fmaf(v - W_A, 2.0f / AB, -1.0f);
    const bool inside = (x >= -1.0f) && (x <= 1.0f);
    x = fminf(fmaxf(x, -1.0f), 1.0f);

    // ---- exp (no max-subtract; inputs ~0.54 +/- 0.3) ----
    const float ew0 = __expf(dw.x + ww.x), ew1 = __expf(dw.y + ww.y);
    const float ew2 = __expf(dw.z + ww.z), ew3 = __expf(dw.w + ww.w);
    const float eh0 = __expf(dh.x + wh.x), eh1 = __expf(dh.y + wh.y);
    const float eh2 = __expf(dh.z + wh.z), eh3 = __expf(dh.w + wh.w);

    // ---- Sw: 16-lane xor-butterfly (per group) ----
    float Sw = (ew0 + ew1) + (ew2 + ew3);
    Sw += swz_f<0x041F>(Sw); Sw += swz_f<0x081F>(Sw);
    Sw += swz_f<0x101F>(Sw); Sw += swz_f<0x201F>(Sw);

    // ---- h: 64-point inclusive cumsum across 16 lanes x 4 regs ----
    float c0 = eh0, c1 = c0 + eh1, c2 = c1 + eh2, c3 = c2 + eh3;
    float t = c3;                           // lane total
    t = dpp_add<0x111>(t);                  // row_shr:1
    t = dpp_add<0x112>(t);                  // row_shr:2
    t = dpp_add<0x114>(t);                  // row_shr:4
    t = dpp_add<0x118>(t);                  // row_shr:8  -> 16-lane inclusive scan
    const float base = t - c3;              // exclusive prefix for this lane
    c0 += base; c1 += base; c2 += base; c3 += base;
    const float Sh = swz_f<0x1F0>(c3);      // broadcast lane15 (group total)

    const float wsc2 = __fdividef(2.0f * (1.0f - 64.0f * MIN_W), Sw);
    const float hsc2 = __fdividef(2.0f * (1.0f - 64.0f * MIN_H), Sh);

    // ---- bin index: count interior right-edges <= x (positions 0..62) ----
    const float off2 = 2.0f * MIN_H;
    const float p1 = (float)(cb + 1);
    const float e0v = fmaf(hsc2, c0, fmaf(off2, p1,          -1.0f));
    const float e1v = fmaf(hsc2, c1, fmaf(off2, p1 + 1.0f,   -1.0f));
    const float e2v = fmaf(hsc2, c2, fmaf(off2, p1 + 2.0f,   -1.0f));
    float       e3v = fmaf(hsc2, c3, fmaf(off2, p1 + 3.0f,   -1.0f));
    if (sub == 15) e3v = 2.0f;              // position 63: edge is 1+1e-6, never taken
    int cnt = (x >= e0v) + (x >= e1v) + (x >= e2v) + (x >= e3v);
    cnt += swz_i<0x041F>(cnt); cnt += swz_i<0x081F>(cnt);
    cnt += swz_i<0x101F>(cnt); cnt += swz_i<0x201F>(cnt);
    const int idx = cnt;                    // group-uniform, 0..63

    // ---- capEh = cumsum_h[idx-1] via bpermute of the 4 cum regs ----
    const int j  = idx - 1;
    const int q  = (j >> 2) & 15;
    const int ad = (grp * 16 + q) << 2;
    const float g0 = __int_as_float(__builtin_amdgcn_ds_bpermute(ad, __float_as_int(c0)));
    const float g1 = __int_as_float(__builtin_amdgcn_ds_bpermute(ad, __float_as_int(c1)));
    const float g2 = __int_as_float(__builtin_amdgcn_ds_bpermute(ad, __float_as_int(c2)));
    const float g3 = __int_as_float(__builtin_amdgcn_ds_bpermute(ad, __float_as_int(c3)));
    const int r = j & 3;
    float sel = (r == 0) ? g0 : (r == 1) ? g1 : (r == 2) ? g2 : g3;
    const float capEh = (idx == 0) ? 0.0f : sel;

    // ---- group-uniform broadcast reloads (L1-hot lines just fetched) ----
    const float ew_i = __expf(dsr[idx]      + swr[idx]);
    const float eh_i = __expf(dsr[64 + idx] + swr[64 + idx]);
    const int cd0 = 127 + (idx > 1 ? idx : 1);          // d0 col (idx>=1)
    const int cd1 = 128 + (idx < 62 ? idx : 62);        // d1 col (idx<=62), stays in-row
    const float u0 = dsr[cd0] + swr[cd0];
    const float u1 = dsr[cd1] + swr[cd1];
    const float d0 = (idx == 0)  ? 1.0f : (MIN_D + __logf(1.0f + __expf(u0)));
    const float d1 = (idx == 63) ? 1.0f : (MIN_D + __logf(1.0f + __expf(u1)));

    // ---- RQS inverse logdet ----
    const float in_w = fmaf(wsc2, ew_i, 2.0f * MIN_W);
    const float in_h = fmaf(hsc2, eh_i, 2.0f * MIN_H);
    const float ch_l = fmaf(hsc2, capEh, fmaf(off2, (float)idx, -1.0f));

    const float delta = __fdividef(in_h, in_w);
    const float dy = x - ch_l;
    const float ss = d0 + d1 - 2.0f * delta;
    const float aa = dy * ss + in_h * (delta - d0);
    const float bb = in_h * d0 - dy * ss;
    const float cc = -delta * dy;
    const float disc = bb * bb - 4.0f * aa * cc;
    const float root = __fdividef(2.0f * cc, -bb - sqrtf(fmaxf(disc, 0.0f)));
    const float tom = root * (1.0f - root);
    const float denom = delta + ss * tom;
    const float omr = 1.0f - root;
    const float dnum = delta * delta * (d1 * root * root + 2.0f * delta * tom + d0 * omr * omr);
    const float logabsdet = -(__logf(dnum) - 2.0f * __logf(denom));

    if (sub == 0 && ii < (long)n)
        out[ii] = LOG_HALF + (inside ? logabsdet : 0.0f) - LOG_AB;
}

extern "C" void kernel_launch(void* const* d_in, const int* in_sizes, int n_in,
                              void* d_out, int out_size, void* d_ws, size_t ws_size,
                              hipStream_t stream) {
    const float* value         = (const float*)d_in[0];
    const float* delta_spline  = (const float*)d_in[1];
    const int*   genes_oi      = (const int*)d_in[2];
    const int*   local_gene_ix = (const int*)d_in[3];
    const float* spline_weight = (const float*)d_in[4];
    float* out = (float*)d_out;

    const int n = in_sizes[0];
    const int cuts_per_block = 16;          // 4 waves x 4 cuts
    const int blocks = (n + cuts_per_block - 1) / cuts_per_block;
    rqs_g16_kernel<<<blocks, 256, 0, stream>>>(
        value, delta_spline, genes_oi, local_gene_ix, spline_weight, out, n);
}

// Round 5
// 499.856 us; speedup vs baseline: 1.1716x; 1.0022x over previous
//
#include <hip/hip_runtime.h>

#define NSPL 191                 // 3*64 - 1 spline dims
constexpr float MIN_W = 0.001f, MIN_H = 0.001f, MIN_D = 0.001f;
constexpr float W_A = -10000.0f, AB = 20000.0f;
constexpr float LOG_HALF = -0.69314718055994530942f;
constexpr float LOG_AB   = 9.90348755253612804622f;   // ln(20000)

// 4-float vectors: unaligned (row bases are 4B-aligned only) and 16B (LDS)
typedef float f4  __attribute__((ext_vector_type(4), aligned(4)));
typedef float f4a __attribute__((ext_vector_type(4), aligned(16)));

// DPP add within 16-lane rows; bound_ctrl=1 -> shifted-in lanes contribute 0
template<int CTRL>
__device__ __forceinline__ float dpp_add(float x) {
    int t = __builtin_amdgcn_update_dpp(0, __float_as_int(x), CTRL, 0xf, 0xf, true);
    return x + __int_as_float(t);
}
template<int PAT>
__device__ __forceinline__ float swz_f(float x) {
    return __int_as_float(__builtin_amdgcn_ds_swizzle(__float_as_int(x), PAT));
}
template<int PAT>
__device__ __forceinline__ int swz_i(int x) {
    return __builtin_amdgcn_ds_swizzle(x, PAT);
}

// 16 lanes per cut (group). Lane sub owns bins 4*sub..4*sub+3.
// Full-row streaming; epilogue gathers via per-group LDS slab (no late global loads).
__global__ __launch_bounds__(256, 4) void rqs_g16_kernel(
    const float* __restrict__ value,
    const float* __restrict__ dsg,       // delta_spline [n,191]
    const int*   __restrict__ genes_oi,
    const int*   __restrict__ lgi,
    const float* __restrict__ swg,       // spline_weight [5000,191]
    float* __restrict__ out, int n)
{
    // per-group slab: [0..63]=h-cumsum C, [64..127]=ew, [128..191]=raw ud u
    __shared__ float lds[16 * 192];

    const int sub = threadIdx.x & 15;
    const int gid = threadIdx.x >> 4;                 // 0..15 (group in block)
    const long ii = (long)blockIdx.x * 16 + gid;      // cut index
    const int  ic = (int)(ii < (long)n ? ii : (long)(n - 1));

    const int g = genes_oi[lgi[ic]];
    const float v = value[ic];

    const float* __restrict__ dsr = dsg + (long)ic * NSPL;
    const float* __restrict__ swr = swg + (long)g  * NSPL;
    float* __restrict__ gl = lds + gid * 192;

    // ---- full-row streaming: w quad, h quad, ud quad (cols 127..190) ----
    const int cb = 4 * sub;
    const f4 dw = *(const f4*)(dsr + cb);
    const f4 dh = *(const f4*)(dsr + 64 + cb);
    const f4 du = *(const f4*)(dsr + 127 + cb);       // padded idx m = cb..cb+3 (m=0 unused)
    const f4 ww = *(const f4*)(swr + cb);
    const f4 wh = *(const f4*)(swr + 64 + cb);
    const f4 wu = *(const f4*)(swr + 127 + cb);

    // raw ud (no softplus here) -> LDS
    *(f4a*)(gl + 128 + cb) = (f4a){du.x + wu.x, du.y + wu.y, du.z + wu.z, du.w + wu.w};

    // ---- x ----
    float x = fmaf(v - W_A, 2.0f / AB, -1.0f);
    const bool inside = (x >= -1.0f) && (x <= 1.0f);
    x = fminf(fmaxf(x, -1.0f), 1.0f);

    // ---- exp (no max-subtract; inputs ~0.54 +/- 0.3) ----
    const float ew0 = __expf(dw.x + ww.x), ew1 = __expf(dw.y + ww.y);
    const float ew2 = __expf(dw.z + ww.z), ew3 = __expf(dw.w + ww.w);
    const float eh0 = __expf(dh.x + wh.x), eh1 = __expf(dh.y + wh.y);
    const float eh2 = __expf(dh.z + wh.z), eh3 = __expf(dh.w + wh.w);

    *(f4a*)(gl + 64 + cb) = (f4a){ew0, ew1, ew2, ew3};

    // ---- Sw: 16-lane xor-butterfly ----
    float Sw = (ew0 + ew1) + (ew2 + ew3);
    Sw += swz_f<0x041F>(Sw); Sw += swz_f<0x081F>(Sw);
    Sw += swz_f<0x101F>(Sw); Sw += swz_f<0x201F>(Sw);

    // ---- h: 64-point inclusive cumsum (4 regs x 16 lanes via DPP row scan) ----
    float c0 = eh0, c1 = c0 + eh1, c2 = c1 + eh2, c3 = c2 + eh3;
    float t = c3;
    t = dpp_add<0x111>(t);   // row_shr:1
    t = dpp_add<0x112>(t);   // row_shr:2
    t = dpp_add<0x114>(t);   // row_shr:4
    t = dpp_add<0x118>(t);   // row_shr:8  -> 16-lane inclusive scan of lane totals
    const float base = t - c3;
    c0 += base; c1 += base; c2 += base; c3 += base;

    *(f4a*)(gl + cb) = (f4a){c0, c1, c2, c3};

    const float Sh = swz_f<0x1F0>(c3);     // broadcast lane 15 (group total)

    const float wsc2 = __fdividef(2.0f * (1.0f - 64.0f * MIN_W), Sw);
    const float hsc2 = __fdividef(2.0f * (1.0f - 64.0f * MIN_H), Sh);

    // ---- bin index: count interior right-edges <= x (positions 1..63) ----
    const float off2 = 2.0f * MIN_H;
    const float p1 = (float)(cb + 1);
    const float e0v = fmaf(hsc2, c0, fmaf(off2, p1,        -1.0f));
    const float e1v = fmaf(hsc2, c1, fmaf(off2, p1 + 1.0f, -1.0f));
    const float e2v = fmaf(hsc2, c2, fmaf(off2, p1 + 2.0f, -1.0f));
    float       e3v = fmaf(hsc2, c3, fmaf(off2, p1 + 3.0f, -1.0f));
    if (sub == 15) e3v = 2.0f;             // edge 63 is 1+1e-6: never taken
    int cnt = (x >= e0v) + (x >= e1v) + (x >= e2v) + (x >= e3v);
    cnt += swz_i<0x041F>(cnt); cnt += swz_i<0x081F>(cnt);
    cnt += swz_i<0x101F>(cnt); cnt += swz_i<0x201F>(cnt);
    const int idx = cnt;                   // group-uniform, 0..63

    // ---- epilogue gathers from LDS (same-wave DS ordering, no barrier) ----
    const float capEh_r = gl[(idx > 0) ? (idx - 1) : 0];
    const float capEh   = (idx == 0) ? 0.0f : capEh_r;
    const float C_idx   = gl[idx];
    const float eh_i    = C_idx - capEh;
    const float ew_i    = gl[64 + idx];
    const float u_d0    = gl[128 + idx];               // m = idx   (used when idx>=1)
    const float u_d1    = gl[128 + ((idx + 1) & 63)];  // m = idx+1 (used when idx<=62)
    const float d0 = (idx == 0)  ? 1.0f : (MIN_D + __logf(1.0f + __expf(u_d0)));
    const float d1 = (idx == 63) ? 1.0f : (MIN_D + __logf(1.0f + __expf(u_d1)));

    // ---- RQS inverse logdet ----
    const float in_w = fmaf(wsc2, ew_i, 2.0f * MIN_W);
    const float in_h = fmaf(hsc2, eh_i, 2.0f * MIN_H);
    const float ch_l = fmaf(hsc2, capEh, fmaf(off2, (float)idx, -1.0f));

    const float delta = __fdividef(in_h, in_w);
    const float dy = x - ch_l;
    const float ss = d0 + d1 - 2.0f * delta;
    const float aa = dy * ss + in_h * (delta - d0);
    const float bb = in_h * d0 - dy * ss;
    const float cc = -delta * dy;
    const float disc = bb * bb - 4.0f * aa * cc;
    const float root = __fdividef(2.0f * cc, -bb - sqrtf(fmaxf(disc, 0.0f)));
    const float tom = root * (1.0f - root);
    const float denom = delta + ss * tom;
    const float omr = 1.0f - root;
    const float dnum = delta * delta * (d1 * root * root + 2.0f * delta * tom + d0 * omr * omr);
    const float logabsdet = -(__logf(dnum) - 2.0f * __logf(denom));

    if (sub == 0 && ii < (long)n)
        out[ii] = LOG_HALF + (inside ? logabsdet : 0.0f) - LOG_AB;
}

extern "C" void kernel_launch(void* const* d_in, const int* in_sizes, int n_in,
                              void* d_out, int out_size, void* d_ws, size_t ws_size,
                              hipStream_t stream) {
    const float* value         = (const float*)d_in[0];
    const float* delta_spline  = (const float*)d_in[1];
    const int*   genes_oi      = (const int*)d_in[2];
    const int*   local_gene_ix = (const int*)d_in[3];
    const float* spline_weight = (const float*)d_in[4];
    float* out = (float*)d_out;

    const int n = in_sizes[0];
    const int cuts_per_block = 16;          // 4 waves x 4 groups
    const int blocks = (n + cuts_per_block - 1) / cuts_per_block;
    rqs_g16_kernel<<<blocks, 256, 0, stream>>>(
        value, delta_spline, genes_oi, local_gene_ix, spline_weight, out, n);
}